// Round 23
// baseline (2417.437 us; speedup 1.0000x reference)
//
#include <hip/hip_runtime.h>
#include <math.h>

#define NROWS  65536
#define DDIM   256
#define KCODES 512
#define NTH    512
#define NSTAGE 3
#define MARGIN  0.5f
#define MAXFLAG 65536
#define NLOSS   256
#define MB      64
#define RB      8
#define NBLK_FINAL (NROWS / 4)

typedef __attribute__((ext_vector_type(8))) short short8v;
typedef __attribute__((ext_vector_type(4))) float f32x4;

__device__ __forceinline__ unsigned short f2bf(float x) {
  unsigned int u = __float_as_uint(x);
  unsigned int r = (u + 0x7fffu + ((u >> 16) & 1u)) >> 16;
  return (unsigned short)r;
}

// ---- np.sum(x*x,-1) model: dispatched pairwise_sum, AVX512F (r12 PASS — do not touch)
__device__ __forceinline__ float np_sumsq256(const float* p) {
#pragma clang fp contract(off)
  float blk[2];
#pragma unroll
  for (int b = 0; b < 2; ++b) {
    const float* a = p + b * 128;
    float v[16];
#pragma unroll
    for (int l = 0; l < 16; ++l) {
      float p0a = a[l] * a[l];
      float p0b = a[64 + l] * a[64 + l];
      float P0 = p0a + p0b;
      float p1a = a[16 + l] * a[16 + l];
      float p1b = a[80 + l] * a[80 + l];
      float P1 = p1a + p1b;
      float p2a = a[32 + l] * a[32 + l];
      float p2b = a[96 + l] * a[96 + l];
      float P2 = p2a + p2b;
      float p3a = a[48 + l] * a[48 + l];
      float p3b = a[112 + l] * a[112 + l];
      float P3 = p3a + p3b;
      v[l] = (P0 + P1) + (P2 + P3);
    }
    float s1[8];
#pragma unroll
    for (int l = 0; l < 8; ++l) s1[l] = v[l] + v[l + 8];
    float s2[4];
#pragma unroll
    for (int l = 0; l < 4; ++l) s2[l] = s1[l] + s1[l + 4];
    float s3_0 = s2[0] + s2[2];
    float s3_1 = s2[1] + s2[3];
    blk[b] = s3_0 + s3_1;
  }
  return blk[0] + blk[1];
}

// ---------------- prep: codebook norms (np-bitwise) + bf16 split frag-ordered ----
__global__ void prep_k(const float* __restrict__ c0, const float* __restrict__ c1,
                       const float* __restrict__ c2, float* __restrict__ cc,
                       unsigned short* __restrict__ Ch) {
  int t = blockIdx.x * 256 + threadIdx.x;
  if (t >= NSTAGE * KCODES * 32) return;
  int s = t / (KCODES * 32);
  int rem = t - s * KCODES * 32;
  int code = rem >> 5;
  int gran = rem & 31;
  int chunk = gran >> 2;
  int g = gran & 3;
  int ctile = code >> 6;
  int ct = (code >> 4) & 3;
  int c16 = code & 15;
  const float* cb = (s == 0) ? c0 : (s == 1 ? c1 : c2);
  const float* src = cb + (size_t)code * DDIM + gran * 8;
  unsigned short hv[8];
#pragma unroll
  for (int j = 0; j < 8; ++j) hv[j] = f2bf(src[j]);
  size_t off = (size_t)s * 262144 +
               ((((size_t)(ctile * 8 + chunk) * 4 + ct) * 64) + (g * 16 + c16)) * 16;
  *(uint4*)((char*)Ch + off) = *(uint4*)hv;
  if (t < NSTAGE * KCODES) {
    const float* cb2p = (t < KCODES) ? c0 : (t < 2 * KCODES ? c1 : c2);
    cc[t] = np_sumsq256(cb2p + (size_t)(t & (KCODES - 1)) * DDIM);
  }
}

// ---------------- gemm_k: in-LDS chain prologue + single-pass bf16 + top-2 ----
#define A_H_OFF 0
#define RED_OFF 32768
#define SMEM_SZ 40960

__global__ __launch_bounds__(NTH, 1) void gemm_k(
    const float* __restrict__ data,
    const unsigned short* __restrict__ Chf,
    const float* __restrict__ cbA, const float* __restrict__ cbB,
    const int* __restrict__ idxA, const int* __restrict__ idxB,
    const float* __restrict__ ccs, int stage,
    int* __restrict__ idx_out, unsigned int* __restrict__ flagcnt,
    int* __restrict__ flagrows) {
  __shared__ char smem[SMEM_SZ];

  const int tid = threadIdx.x;
  const int lane = tid & 63;
  const int w = tid >> 6;
  const int rowbase = blockIdx.x * MB;

  // ---- prologue: residual chain (np f32, r12-verified op order) -> bf16 hi -> LDS
  for (int iter = 0; iter < 8; ++iter) {
    const int lr = iter * 8 + w;       // wave-uniform row
    const int r = rowbase + lr;
    const int k = lane * 4;
    float res[4];
    {
#pragma clang fp contract(off)
      const size_t base = (size_t)r * DDIM + k;
      float4 dv = *(const float4*)(data + base);
      float x1[4] = {dv.x, dv.y, dv.z, dv.w};
      if (stage == 0) {
#pragma unroll
        for (int j = 0; j < 4; ++j) res[j] = x1[j];
      } else {
        const int iA = idxA[r];
        float4 av = *(const float4*)(cbA + (size_t)iA * DDIM + k);
        float af[4] = {av.x, av.y, av.z, av.w};
        float a[4];
#pragma unroll
        for (int j = 0; j < 4; ++j) a[j] = x1[j] + (af[j] - x1[j]);
        if (stage == 2) {
          const int iB = idxB[r];
          float4 bv = *(const float4*)(cbB + (size_t)iB * DDIM + k);
          float bf[4] = {bv.x, bv.y, bv.z, bv.w};
#pragma unroll
          for (int j = 0; j < 4; ++j) {
            float x2 = x1[j] - a[j];
            float qst2 = x2 + (bf[j] - x2);
            a[j] = a[j] + qst2;
          }
        }
#pragma unroll
        for (int j = 0; j < 4; ++j) res[j] = x1[j] - a[j];
      }
    }
    unsigned short h4[4];
#pragma unroll
    for (int j = 0; j < 4; ++j) h4[j] = f2bf(res[j]);
    const int byte = ((lr * 512 + (k >> 3) * 16) ^ ((lr & 7) << 4)) + ((k & 4) << 1);
    *(ushort4*)(smem + A_H_OFF + byte) = *(ushort4*)h4;
  }

  f32x4 acc[4][4];
#pragma unroll
  for (int rt = 0; rt < 4; ++rt)
#pragma unroll
    for (int ct = 0; ct < 4; ++ct) {
      acc[rt][ct].x = 0.f; acc[rt][ct].y = 0.f;
      acc[rt][ct].z = 0.f; acc[rt][ct].w = 0.f;
    }

  const int g = lane >> 4, c16 = lane & 15;
  const char* bhw = (const char*)Chf + lane * 16;

  __syncthreads();   // A tile visible

#pragma clang loop unroll(disable)
  for (int chunk = 0; chunk < 8; ++chunk) {
    short8v ah[4];
#pragma unroll
    for (int rt = 0; rt < 4; ++rt) {
      const int row = rt * 16 + c16;
      const int byte = (row * 512 + (chunk * 4 + g) * 16) ^ ((row & 7) << 4);
      ah[rt] = *(short8v*)(smem + A_H_OFF + byte);
    }
#pragma unroll
    for (int ct = 0; ct < 4; ++ct) {
      short8v bh = *(const short8v*)(bhw + (size_t)((w * 8 + chunk) * 4 + ct) * 1024);
#pragma unroll
      for (int rt = 0; rt < 4; ++rt)
        acc[rt][ct] = __builtin_amdgcn_mfma_f32_16x16x32_bf16(ah[rt], bh, acc[rt][ct], 0, 0, 0);
    }
  }
  __syncthreads();   // A reads done; red reuse safe

  float ccv[4];
#pragma unroll
  for (int ct = 0; ct < 4; ++ct) ccv[ct] = ccs[w * 64 + ct * 16 + c16];

  float* red = (float*)(smem + RED_OFF);
#pragma unroll
  for (int rt = 0; rt < 4; ++rt) {
#pragma unroll
    for (int reg = 0; reg < 4; ++reg) {
      const int row = rt * 16 + g * 4 + reg;
      float v1 = 3.0e38f, v2 = 3.0e38f;
      int i1 = 0x7fffffff;
#pragma unroll
      for (int ct = 0; ct < 4; ++ct) {
        const int col = w * 64 + ct * 16 + c16;
        float dd = ccv[ct] - 2.0f * acc[rt][ct][reg];
        if (dd < v1 || (dd == v1 && col < i1)) { v2 = v1; v1 = dd; i1 = col; }
        else if (dd < v2) v2 = dd;
      }
#pragma unroll
      for (int m = 1; m < 16; m <<= 1) {
        float ov1 = __shfl_xor(v1, m, 64);
        int oi1 = __shfl_xor(i1, m, 64);
        float ov2 = __shfl_xor(v2, m, 64);
        float worst = fmaxf(v1, ov1);
        v2 = fminf(fminf(v2, ov2), worst);
        if (ov1 < v1 || (ov1 == v1 && oi1 < i1)) { v1 = ov1; i1 = oi1; }
      }
      if (c16 == 0) {
        float* slot = red + (size_t)(row * 8 + w) * 4;
        slot[0] = v1;
        ((int*)slot)[1] = i1;
        slot[2] = v2;
      }
    }
  }
  __syncthreads();
  if (tid < MB) {
    float v1 = 3.0e38f, v2 = 3.0e38f;
    int i1 = 0x7fffffff;
#pragma unroll
    for (int ww = 0; ww < 8; ++ww) {
      const float* slot = red + (size_t)(tid * 8 + ww) * 4;
      float ov1 = slot[0];
      int oi1 = ((const int*)slot)[1];
      float ov2 = slot[2];
      float worst = fmaxf(v1, ov1);
      v2 = fminf(fminf(v2, ov2), worst);
      if (ov1 < v1 || (ov1 == v1 && oi1 < i1)) { v1 = ov1; i1 = oi1; }
    }
    const int r = rowbase + tid;
    idx_out[r] = i1;
    if (v2 - v1 < MARGIN) {
      unsigned pos = atomicAdd(flagcnt, 1u);
      if (pos < MAXFLAG) flagrows[pos] = r;
    }
  }
}

// ---------------- refine v2 (r21 PASS, unchanged): batched RB rows, np-bitwise ----
__global__ __launch_bounds__(256) void refine_k(
    const float* __restrict__ data, const float* __restrict__ cb,
    const float* __restrict__ cbA, const float* __restrict__ cbB,
    const int* __restrict__ idxA, const int* __restrict__ idxB,
    const float* __restrict__ ccs, int stage,
    const unsigned int* __restrict__ flagcnt, const int* __restrict__ flagrows,
    int* __restrict__ idx_out) {
  __shared__ float rows[RB][DDIM];
  __shared__ float xxs[RB];
  __shared__ float red_v[RB][256];
  __shared__ int red_i[RB][256];

  unsigned int n = *flagcnt;
  if (n > MAXFLAG) n = MAXFLAG;
  const int tid = threadIdx.x;

  for (unsigned base = (unsigned)blockIdx.x * RB; base < n;
       base += (unsigned)gridDim.x * RB) {
    const int nb = (int)min((unsigned)RB, n - base);

    for (int u = tid; u < nb * 64; u += 256) {
#pragma clang fp contract(off)
      const int i = u >> 6;
      const int c4 = (u & 63) * 4;
      const int r = flagrows[base + i];
      const size_t gbase = (size_t)r * DDIM + c4;
      float4 dv = *(const float4*)(data + gbase);
      float x1[4] = {dv.x, dv.y, dv.z, dv.w};
      float res[4];
      if (stage == 0) {
#pragma unroll
        for (int j = 0; j < 4; ++j) res[j] = x1[j];
      } else {
        const int iA = idxA[r];
        float4 av = *(const float4*)(cbA + (size_t)iA * DDIM + c4);
        float af[4] = {av.x, av.y, av.z, av.w};
        float a[4];
#pragma unroll
        for (int j = 0; j < 4; ++j) a[j] = x1[j] + (af[j] - x1[j]);
        if (stage == 2) {
          const int iB = idxB[r];
          float4 bv = *(const float4*)(cbB + (size_t)iB * DDIM + c4);
          float bf[4] = {bv.x, bv.y, bv.z, bv.w};
#pragma unroll
          for (int j = 0; j < 4; ++j) {
            float x2 = x1[j] - a[j];
            float qst2 = x2 + (bf[j] - x2);
            a[j] = a[j] + qst2;
          }
        }
#pragma unroll
        for (int j = 0; j < 4; ++j) res[j] = x1[j] - a[j];
      }
#pragma unroll
      for (int j = 0; j < 4; ++j) rows[i][c4 + j] = res[j];
    }
    __syncthreads();
    if (tid < nb) xxs[tid] = np_sumsq256(rows[tid]);
    __syncthreads();

    float bv[RB];
    int bi[RB];
#pragma unroll
    for (int i = 0; i < RB; ++i) { bv[i] = 3.0e38f; bi[i] = 0x7fffffff; }

#pragma clang loop unroll(disable)
    for (int h = 0; h < 2; ++h) {
#pragma clang fp contract(off)
      const int k = tid + h * 256;
      const float* crow = cb + (size_t)k * DDIM;
      float v[RB][4];
#pragma unroll
      for (int i = 0; i < RB; ++i)
#pragma unroll
        for (int l = 0; l < 4; ++l) v[i][l] = 0.f;

#pragma clang loop unroll(disable)
      for (int t = 0; t < 16; ++t) {
        float b[16];
#pragma unroll
        for (int j = 0; j < 16; ++j) b[j] = crow[t * 16 + j];
#pragma unroll
        for (int i = 0; i < RB; ++i) {
#pragma unroll
          for (int l = 0; l < 4; ++l) {
            float a0 = rows[i][t * 16 + l];
            float a1 = rows[i][t * 16 + 4 + l];
            float a2 = rows[i][t * 16 + 8 + l];
            float a3 = rows[i][t * 16 + 12 + l];
            float ab3 = a3 * b[12 + l] + v[i][l];
            float ab2 = a2 * b[8 + l] + ab3;
            float ab1 = a1 * b[4 + l] + ab2;
            v[i][l] = a0 * b[l] + ab1;
          }
        }
      }
      const float cck = ccs[k];
#pragma unroll
      for (int i = 0; i < RB; ++i) {
        float dot = (v[i][0] + v[i][1]) + (v[i][2] + v[i][3]);
        float t1 = xxs[i] - 2.0f * dot;
        float d = t1 + cck;
        if (d < bv[i] || (d == bv[i] && k < bi[i])) { bv[i] = d; bi[i] = k; }
      }
    }

#pragma unroll
    for (int i = 0; i < RB; ++i) { red_v[i][tid] = bv[i]; red_i[i][tid] = bi[i]; }
    __syncthreads();
    for (int gap = 128; gap > 0; gap >>= 1) {
      if (tid < gap) {
#pragma unroll
        for (int i = 0; i < RB; ++i) {
          float o = red_v[i][tid + gap];
          int oi = red_i[i][tid + gap];
          if (o < red_v[i][tid] || (o == red_v[i][tid] && oi < red_i[i][tid])) {
            red_v[i][tid] = o;
            red_i[i][tid] = oi;
          }
        }
      }
      __syncthreads();
    }
    if (tid < nb) idx_out[flagrows[base + tid]] = red_i[tid][0];
    __syncthreads();
  }
}

// ---------------- final: quant + loss + hist + one-hot scatter + fused scalars ----
__global__ __launch_bounds__(256) void final_k(
    const float* __restrict__ data, const float* __restrict__ cb0,
    const float* __restrict__ cb1, const float* __restrict__ cb2,
    const int* __restrict__ idx0, const int* __restrict__ idx1,
    const int* __restrict__ idx2, float* __restrict__ quant,
    float* __restrict__ enc0, float* __restrict__ enc1,
    float* __restrict__ enc2, double* __restrict__ loss_slots,
    unsigned int* __restrict__ hist, unsigned int* __restrict__ done,
    float* __restrict__ out_scalars) {
  __shared__ double wsum[4];
  const int lane = threadIdx.x & 63;
  const int w = threadIdx.x >> 6;
  const int r = blockIdx.x * 4 + w;
  const int i0 = idx0[r], i1 = idx1[r], i2 = idx2[r];
  const size_t base = (size_t)r * DDIM + lane * 4;
  float4 dv = *(const float4*)(data + base);
  float4 c0v = *(const float4*)(cb0 + (size_t)i0 * DDIM + lane * 4);
  float4 c1v = *(const float4*)(cb1 + (size_t)i1 * DDIM + lane * 4);
  float4 c2v = *(const float4*)(cb2 + (size_t)i2 * DDIM + lane * 4);
  float df[4] = {dv.x, dv.y, dv.z, dv.w};
  float q0f[4] = {c0v.x, c0v.y, c0v.z, c0v.w};
  float q1f[4] = {c1v.x, c1v.y, c1v.z, c1v.w};
  float q2f[4] = {c2v.x, c2v.y, c2v.z, c2v.w};
  float qout[4];
  double lsum = 0.0;
  {
#pragma clang fp contract(off)
#pragma unroll
    for (int j = 0; j < 4; ++j) {
      float x1 = df[j];
      float d1 = q0f[j] - x1;
      float qst1 = x1 + d1;
      float a1 = qst1;
      float x2 = x1 - a1;
      float d2 = q1f[j] - x2;
      float qst2 = x2 + d2;
      float a2 = a1 + qst2;
      float x3 = x1 - a2;
      float d3 = q2f[j] - x3;
      float qst3 = x3 + d3;
      float a3 = a2 + qst3;
      qout[j] = a3;
      lsum += (double)d1 * d1 + (double)d2 * d2 + (double)d3 * d3;
    }
  }
  float4 qv = {qout[0], qout[1], qout[2], qout[3]};
  *(float4*)(quant + base) = qv;

#pragma unroll
  for (int off = 1; off < 64; off <<= 1) lsum += __shfl_xor(lsum, off, 64);
  if (lane == 0) {
    wsum[w] = lsum;
    enc0[(size_t)r * KCODES + i0] = 1.0f;
    atomicAdd(&hist[i0], 1u);
  } else if (lane == 1) {
    enc1[(size_t)r * KCODES + i1] = 1.0f;
    atomicAdd(&hist[KCODES + i1], 1u);
  } else if (lane == 2) {
    enc2[(size_t)r * KCODES + i2] = 1.0f;
    atomicAdd(&hist[2 * KCODES + i2], 1u);
  }
  __syncthreads();
  if (threadIdx.x == 0) {
    double bsum = (wsum[0] + wsum[1]) + (wsum[2] + wsum[3]);
    atomicAdd(&loss_slots[blockIdx.x & (NLOSS - 1)], bsum);
  }
  // ---- last-block fused finalize
  __threadfence();
  __shared__ unsigned int amlast;
  if (threadIdx.x == 0) amlast = atomicAdd(done, 1u);
  __syncthreads();
  if (amlast == NBLK_FINAL - 1 && threadIdx.x < 64) {
    const int l2 = threadIdx.x;
    double te = 0.0;
    for (int s = 0; s < NSTAGE; ++s) {
      double e = 0.0;
      for (int j = 0; j < KCODES / 64; ++j) {
        int k = j * 64 + l2;
        float pf = (float)hist[s * KCODES + k] * (1.0f / 65536.0f);
        float sf = __fadd_rn(pf, 1e-10f);
        e += (double)pf * log((double)sf);
      }
#pragma unroll
      for (int off = 1; off < 64; off <<= 1) e += __shfl_xor(e, off, 64);
      te += -e;
    }
    double ls = loss_slots[l2] + loss_slots[64 + l2] +
                loss_slots[128 + l2] + loss_slots[192 + l2];
#pragma unroll
    for (int off = 1; off < 64; off <<= 1) ls += __shfl_xor(ls, off, 64);
    if (l2 == 0) {
      double tl = 1.25 * ls * (1.0 / 16777216.0);
      out_scalars[0] = (float)tl;
      out_scalars[1] = (float)te;
    }
  }
}

extern "C" void kernel_launch(void* const* d_in, const int* in_sizes, int n_in,
                              void* d_out, int out_size, void* d_ws, size_t ws_size,
                              hipStream_t stream) {
  const float* data = (const float*)d_in[0];
  const float* cb0 = (const float*)d_in[1];
  const float* cb1 = (const float*)d_in[2];
  const float* cb2 = (const float*)d_in[3];
  const float* cbs[3] = {cb0, cb1, cb2};
  float* out = (float*)d_out;
  float* quant = out;
  float* enc0 = out + (size_t)NROWS * DDIM;
  float* enc1 = enc0 + (size_t)NROWS * KCODES;
  float* enc2 = enc1 + (size_t)NROWS * KCODES;
  float* out_scalars = enc2 + (size_t)NROWS * KCODES;

  // ws: [0) loss_slots f64x256 | 2048) hist u32x1536 | 8192) flagcnt u32x3 |
  //     8204) done u32 | 8320) flagrows i32[3][65536] | 794752) cc f32x1536 |
  //     800896) idx i32[3][N] | 1587328) Ch frag-bf16 3x256KB
  double* loss_slots = (double*)d_ws;
  unsigned int* hist = (unsigned int*)((char*)d_ws + 2048);
  unsigned int* flagcnt = (unsigned int*)((char*)d_ws + 8192);
  unsigned int* done = (unsigned int*)((char*)d_ws + 8204);
  int* flagrows = (int*)((char*)d_ws + 8320);
  float* cc = (float*)((char*)d_ws + 794752);
  int* idx0 = (int*)((char*)d_ws + 800896);
  int* idx1 = idx0 + NROWS;
  int* idx2 = idx1 + NROWS;
  int* idxs[3] = {idx0, idx1, idx2};
  unsigned short* Ch = (unsigned short*)((char*)d_ws + 1587328);

  hipMemsetAsync(d_ws, 0, 8320, stream);

  prep_k<<<(NSTAGE * KCODES * 32 + 255) / 256, 256, 0, stream>>>(
      cb0, cb1, cb2, cc, Ch);

  for (int s = 0; s < NSTAGE; ++s) {
    gemm_k<<<NROWS / MB, NTH, 0, stream>>>(
        data,
        (const unsigned short*)((char*)Ch + (size_t)s * 262144),
        cb0, cb1, idx0, idx1, cc + s * KCODES, s,
        idxs[s], flagcnt + s, flagrows + s * MAXFLAG);
    refine_k<<<512, 256, 0, stream>>>(
        data, cbs[s], cb0, cb1, idx0, idx1, cc + s * KCODES, s,
        flagcnt + s, flagrows + s * MAXFLAG, idxs[s]);
  }

  // zero enc region, then scatter the 1s + fused finalize
  hipMemsetAsync(enc0, 0, (size_t)3 * NROWS * KCODES * sizeof(float), stream);

  final_k<<<NBLK_FINAL, 256, 0, stream>>>(
      data, cb0, cb1, cb2, idx0, idx1, idx2, quant, enc0, enc1, enc2,
      loss_slots, hist, done, out_scalars);
}

// Round 24
// 502.714 us; speedup vs baseline: 4.8088x; 4.8088x over previous
//
#include <hip/hip_runtime.h>
#include <math.h>

#define NROWS  65536
#define DDIM   256
#define KCODES 512
#define NTH    512
#define NSTAGE 3
#define MARGIN  0.5f
#define MAXFLAG 65536
#define NLOSS   256
#define MB      64
#define RB      8

typedef __attribute__((ext_vector_type(8))) short short8v;
typedef __attribute__((ext_vector_type(4))) float f32x4;

__device__ __forceinline__ unsigned short f2bf(float x) {
  unsigned int u = __float_as_uint(x);
  unsigned int r = (u + 0x7fffu + ((u >> 16) & 1u)) >> 16;
  return (unsigned short)r;
}

// ---- np.sum(x*x,-1) model: dispatched pairwise_sum, AVX512F (r12 PASS — do not touch)
__device__ __forceinline__ float np_sumsq256(const float* p) {
#pragma clang fp contract(off)
  float blk[2];
#pragma unroll
  for (int b = 0; b < 2; ++b) {
    const float* a = p + b * 128;
    float v[16];
#pragma unroll
    for (int l = 0; l < 16; ++l) {
      float p0a = a[l] * a[l];
      float p0b = a[64 + l] * a[64 + l];
      float P0 = p0a + p0b;
      float p1a = a[16 + l] * a[16 + l];
      float p1b = a[80 + l] * a[80 + l];
      float P1 = p1a + p1b;
      float p2a = a[32 + l] * a[32 + l];
      float p2b = a[96 + l] * a[96 + l];
      float P2 = p2a + p2b;
      float p3a = a[48 + l] * a[48 + l];
      float p3b = a[112 + l] * a[112 + l];
      float P3 = p3a + p3b;
      v[l] = (P0 + P1) + (P2 + P3);
    }
    float s1[8];
#pragma unroll
    for (int l = 0; l < 8; ++l) s1[l] = v[l] + v[l + 8];
    float s2[4];
#pragma unroll
    for (int l = 0; l < 4; ++l) s2[l] = s1[l] + s1[l + 4];
    float s3_0 = s2[0] + s2[2];
    float s3_1 = s2[1] + s2[3];
    blk[b] = s3_0 + s3_1;
  }
  return blk[0] + blk[1];
}

// ---------------- prep: codebook norms (np-bitwise) + bf16 split frag-ordered ----
__global__ void prep_k(const float* __restrict__ c0, const float* __restrict__ c1,
                       const float* __restrict__ c2, float* __restrict__ cc,
                       unsigned short* __restrict__ Ch) {
  int t = blockIdx.x * 256 + threadIdx.x;
  if (t >= NSTAGE * KCODES * 32) return;
  int s = t / (KCODES * 32);
  int rem = t - s * KCODES * 32;
  int code = rem >> 5;
  int gran = rem & 31;
  int chunk = gran >> 2;
  int g = gran & 3;
  int ctile = code >> 6;
  int ct = (code >> 4) & 3;
  int c16 = code & 15;
  const float* cb = (s == 0) ? c0 : (s == 1 ? c1 : c2);
  const float* src = cb + (size_t)code * DDIM + gran * 8;
  unsigned short hv[8];
#pragma unroll
  for (int j = 0; j < 8; ++j) hv[j] = f2bf(src[j]);
  size_t off = (size_t)s * 262144 +
               ((((size_t)(ctile * 8 + chunk) * 4 + ct) * 64) + (g * 16 + c16)) * 16;
  *(uint4*)((char*)Ch + off) = *(uint4*)hv;
  if (t < NSTAGE * KCODES) {
    const float* cb2p = (t < KCODES) ? c0 : (t < 2 * KCODES ? c1 : c2);
    cc[t] = np_sumsq256(cb2p + (size_t)(t & (KCODES - 1)) * DDIM);
  }
}

// ---------------- gemm_k: in-LDS chain prologue + single-pass bf16 + top-2 ----
#define A_H_OFF 0
#define RED_OFF 32768
#define SMEM_SZ 40960

__global__ __launch_bounds__(NTH, 1) void gemm_k(
    const float* __restrict__ data,
    const unsigned short* __restrict__ Chf,
    const float* __restrict__ cbA, const float* __restrict__ cbB,
    const int* __restrict__ idxA, const int* __restrict__ idxB,
    const float* __restrict__ ccs, int stage,
    int* __restrict__ idx_out, unsigned int* __restrict__ flagcnt,
    int* __restrict__ flagrows) {
  __shared__ char smem[SMEM_SZ];

  const int tid = threadIdx.x;
  const int lane = tid & 63;
  const int w = tid >> 6;
  const int rowbase = blockIdx.x * MB;

  // ---- prologue: residual chain (np f32, r12-verified op order) -> bf16 hi -> LDS
  for (int iter = 0; iter < 8; ++iter) {
    const int lr = iter * 8 + w;       // wave-uniform row
    const int r = rowbase + lr;
    const int k = lane * 4;
    float res[4];
    {
#pragma clang fp contract(off)
      const size_t base = (size_t)r * DDIM + k;
      float4 dv = *(const float4*)(data + base);
      float x1[4] = {dv.x, dv.y, dv.z, dv.w};
      if (stage == 0) {
#pragma unroll
        for (int j = 0; j < 4; ++j) res[j] = x1[j];
      } else {
        const int iA = idxA[r];
        float4 av = *(const float4*)(cbA + (size_t)iA * DDIM + k);
        float af[4] = {av.x, av.y, av.z, av.w};
        float a[4];
#pragma unroll
        for (int j = 0; j < 4; ++j) a[j] = x1[j] + (af[j] - x1[j]);
        if (stage == 2) {
          const int iB = idxB[r];
          float4 bv = *(const float4*)(cbB + (size_t)iB * DDIM + k);
          float bf[4] = {bv.x, bv.y, bv.z, bv.w};
#pragma unroll
          for (int j = 0; j < 4; ++j) {
            float x2 = x1[j] - a[j];
            float qst2 = x2 + (bf[j] - x2);
            a[j] = a[j] + qst2;
          }
        }
#pragma unroll
        for (int j = 0; j < 4; ++j) res[j] = x1[j] - a[j];
      }
    }
    unsigned short h4[4];
#pragma unroll
    for (int j = 0; j < 4; ++j) h4[j] = f2bf(res[j]);
    const int byte = ((lr * 512 + (k >> 3) * 16) ^ ((lr & 7) << 4)) + ((k & 4) << 1);
    *(ushort4*)(smem + A_H_OFF + byte) = *(ushort4*)h4;
  }

  f32x4 acc[4][4];
#pragma unroll
  for (int rt = 0; rt < 4; ++rt)
#pragma unroll
    for (int ct = 0; ct < 4; ++ct) {
      acc[rt][ct].x = 0.f; acc[rt][ct].y = 0.f;
      acc[rt][ct].z = 0.f; acc[rt][ct].w = 0.f;
    }

  const int g = lane >> 4, c16 = lane & 15;
  const char* bhw = (const char*)Chf + lane * 16;

  __syncthreads();   // A tile visible

#pragma clang loop unroll(disable)
  for (int chunk = 0; chunk < 8; ++chunk) {
    short8v ah[4];
#pragma unroll
    for (int rt = 0; rt < 4; ++rt) {
      const int row = rt * 16 + c16;
      const int byte = (row * 512 + (chunk * 4 + g) * 16) ^ ((row & 7) << 4);
      ah[rt] = *(short8v*)(smem + A_H_OFF + byte);
    }
#pragma unroll
    for (int ct = 0; ct < 4; ++ct) {
      short8v bh = *(const short8v*)(bhw + (size_t)((w * 8 + chunk) * 4 + ct) * 1024);
#pragma unroll
      for (int rt = 0; rt < 4; ++rt)
        acc[rt][ct] = __builtin_amdgcn_mfma_f32_16x16x32_bf16(ah[rt], bh, acc[rt][ct], 0, 0, 0);
    }
  }
  __syncthreads();   // A reads done; red reuse safe

  float ccv[4];
#pragma unroll
  for (int ct = 0; ct < 4; ++ct) ccv[ct] = ccs[w * 64 + ct * 16 + c16];

  float* red = (float*)(smem + RED_OFF);
#pragma unroll
  for (int rt = 0; rt < 4; ++rt) {
#pragma unroll
    for (int reg = 0; reg < 4; ++reg) {
      const int row = rt * 16 + g * 4 + reg;
      float v1 = 3.0e38f, v2 = 3.0e38f;
      int i1 = 0x7fffffff;
#pragma unroll
      for (int ct = 0; ct < 4; ++ct) {
        const int col = w * 64 + ct * 16 + c16;
        float dd = ccv[ct] - 2.0f * acc[rt][ct][reg];
        if (dd < v1 || (dd == v1 && col < i1)) { v2 = v1; v1 = dd; i1 = col; }
        else if (dd < v2) v2 = dd;
      }
#pragma unroll
      for (int m = 1; m < 16; m <<= 1) {
        float ov1 = __shfl_xor(v1, m, 64);
        int oi1 = __shfl_xor(i1, m, 64);
        float ov2 = __shfl_xor(v2, m, 64);
        float worst = fmaxf(v1, ov1);
        v2 = fminf(fminf(v2, ov2), worst);
        if (ov1 < v1 || (ov1 == v1 && oi1 < i1)) { v1 = ov1; i1 = oi1; }
      }
      if (c16 == 0) {
        float* slot = red + (size_t)(row * 8 + w) * 4;
        slot[0] = v1;
        ((int*)slot)[1] = i1;
        slot[2] = v2;
      }
    }
  }
  __syncthreads();
  if (tid < MB) {
    float v1 = 3.0e38f, v2 = 3.0e38f;
    int i1 = 0x7fffffff;
#pragma unroll
    for (int ww = 0; ww < 8; ++ww) {
      const float* slot = red + (size_t)(tid * 8 + ww) * 4;
      float ov1 = slot[0];
      int oi1 = ((const int*)slot)[1];
      float ov2 = slot[2];
      float worst = fmaxf(v1, ov1);
      v2 = fminf(fminf(v2, ov2), worst);
      if (ov1 < v1 || (ov1 == v1 && oi1 < i1)) { v1 = ov1; i1 = oi1; }
    }
    const int r = rowbase + tid;
    idx_out[r] = i1;
    if (v2 - v1 < MARGIN) {
      unsigned pos = atomicAdd(flagcnt, 1u);
      if (pos < MAXFLAG) flagrows[pos] = r;
    }
  }
}

// ---------------- refine v2 (r21 PASS, unchanged): batched RB rows, np-bitwise ----
__global__ __launch_bounds__(256) void refine_k(
    const float* __restrict__ data, const float* __restrict__ cb,
    const float* __restrict__ cbA, const float* __restrict__ cbB,
    const int* __restrict__ idxA, const int* __restrict__ idxB,
    const float* __restrict__ ccs, int stage,
    const unsigned int* __restrict__ flagcnt, const int* __restrict__ flagrows,
    int* __restrict__ idx_out) {
  __shared__ float rows[RB][DDIM];
  __shared__ float xxs[RB];
  __shared__ float red_v[RB][256];
  __shared__ int red_i[RB][256];

  unsigned int n = *flagcnt;
  if (n > MAXFLAG) n = MAXFLAG;
  const int tid = threadIdx.x;

  for (unsigned base = (unsigned)blockIdx.x * RB; base < n;
       base += (unsigned)gridDim.x * RB) {
    const int nb = (int)min((unsigned)RB, n - base);

    for (int u = tid; u < nb * 64; u += 256) {
#pragma clang fp contract(off)
      const int i = u >> 6;
      const int c4 = (u & 63) * 4;
      const int r = flagrows[base + i];
      const size_t gbase = (size_t)r * DDIM + c4;
      float4 dv = *(const float4*)(data + gbase);
      float x1[4] = {dv.x, dv.y, dv.z, dv.w};
      float res[4];
      if (stage == 0) {
#pragma unroll
        for (int j = 0; j < 4; ++j) res[j] = x1[j];
      } else {
        const int iA = idxA[r];
        float4 av = *(const float4*)(cbA + (size_t)iA * DDIM + c4);
        float af[4] = {av.x, av.y, av.z, av.w};
        float a[4];
#pragma unroll
        for (int j = 0; j < 4; ++j) a[j] = x1[j] + (af[j] - x1[j]);
        if (stage == 2) {
          const int iB = idxB[r];
          float4 bv = *(const float4*)(cbB + (size_t)iB * DDIM + c4);
          float bf[4] = {bv.x, bv.y, bv.z, bv.w};
#pragma unroll
          for (int j = 0; j < 4; ++j) {
            float x2 = x1[j] - a[j];
            float qst2 = x2 + (bf[j] - x2);
            a[j] = a[j] + qst2;
          }
        }
#pragma unroll
        for (int j = 0; j < 4; ++j) res[j] = x1[j] - a[j];
      }
#pragma unroll
      for (int j = 0; j < 4; ++j) rows[i][c4 + j] = res[j];
    }
    __syncthreads();
    if (tid < nb) xxs[tid] = np_sumsq256(rows[tid]);
    __syncthreads();

    float bv[RB];
    int bi[RB];
#pragma unroll
    for (int i = 0; i < RB; ++i) { bv[i] = 3.0e38f; bi[i] = 0x7fffffff; }

#pragma clang loop unroll(disable)
    for (int h = 0; h < 2; ++h) {
#pragma clang fp contract(off)
      const int k = tid + h * 256;
      const float* crow = cb + (size_t)k * DDIM;
      float v[RB][4];
#pragma unroll
      for (int i = 0; i < RB; ++i)
#pragma unroll
        for (int l = 0; l < 4; ++l) v[i][l] = 0.f;

#pragma clang loop unroll(disable)
      for (int t = 0; t < 16; ++t) {
        float b[16];
#pragma unroll
        for (int j = 0; j < 16; ++j) b[j] = crow[t * 16 + j];
#pragma unroll
        for (int i = 0; i < RB; ++i) {
#pragma unroll
          for (int l = 0; l < 4; ++l) {
            float a0 = rows[i][t * 16 + l];
            float a1 = rows[i][t * 16 + 4 + l];
            float a2 = rows[i][t * 16 + 8 + l];
            float a3 = rows[i][t * 16 + 12 + l];
            float ab3 = a3 * b[12 + l] + v[i][l];
            float ab2 = a2 * b[8 + l] + ab3;
            float ab1 = a1 * b[4 + l] + ab2;
            v[i][l] = a0 * b[l] + ab1;
          }
        }
      }
      const float cck = ccs[k];
#pragma unroll
      for (int i = 0; i < RB; ++i) {
        float dot = (v[i][0] + v[i][1]) + (v[i][2] + v[i][3]);
        float t1 = xxs[i] - 2.0f * dot;
        float d = t1 + cck;
        if (d < bv[i] || (d == bv[i] && k < bi[i])) { bv[i] = d; bi[i] = k; }
      }
    }

#pragma unroll
    for (int i = 0; i < RB; ++i) { red_v[i][tid] = bv[i]; red_i[i][tid] = bi[i]; }
    __syncthreads();
    for (int gap = 128; gap > 0; gap >>= 1) {
      if (tid < gap) {
#pragma unroll
        for (int i = 0; i < RB; ++i) {
          float o = red_v[i][tid + gap];
          int oi = red_i[i][tid + gap];
          if (o < red_v[i][tid] || (o == red_v[i][tid] && oi < red_i[i][tid])) {
            red_v[i][tid] = o;
            red_i[i][tid] = oi;
          }
        }
      }
      __syncthreads();
    }
    if (tid < nb) idx_out[flagrows[base + tid]] = red_i[tid][0];
    __syncthreads();
  }
}

// ---------------- slim final: quant + loss + hist + one-hot SCATTER ----
__global__ __launch_bounds__(256) void final_k(
    const float* __restrict__ data, const float* __restrict__ cb0,
    const float* __restrict__ cb1, const float* __restrict__ cb2,
    const int* __restrict__ idx0, const int* __restrict__ idx1,
    const int* __restrict__ idx2, float* __restrict__ quant,
    float* __restrict__ enc0, float* __restrict__ enc1,
    float* __restrict__ enc2, double* __restrict__ loss_slots,
    unsigned int* __restrict__ hist) {
  __shared__ double wsum[4];
  const int lane = threadIdx.x & 63;
  const int w = threadIdx.x >> 6;
  const int r = blockIdx.x * 4 + w;
  const int i0 = idx0[r], i1 = idx1[r], i2 = idx2[r];
  const size_t base = (size_t)r * DDIM + lane * 4;
  float4 dv = *(const float4*)(data + base);
  float4 c0v = *(const float4*)(cb0 + (size_t)i0 * DDIM + lane * 4);
  float4 c1v = *(const float4*)(cb1 + (size_t)i1 * DDIM + lane * 4);
  float4 c2v = *(const float4*)(cb2 + (size_t)i2 * DDIM + lane * 4);
  float df[4] = {dv.x, dv.y, dv.z, dv.w};
  float q0f[4] = {c0v.x, c0v.y, c0v.z, c0v.w};
  float q1f[4] = {c1v.x, c1v.y, c1v.z, c1v.w};
  float q2f[4] = {c2v.x, c2v.y, c2v.z, c2v.w};
  float qout[4];
  double lsum = 0.0;
  {
#pragma clang fp contract(off)
#pragma unroll
    for (int j = 0; j < 4; ++j) {
      float x1 = df[j];
      float d1 = q0f[j] - x1;
      float qst1 = x1 + d1;
      float a1 = qst1;
      float x2 = x1 - a1;
      float d2 = q1f[j] - x2;
      float qst2 = x2 + d2;
      float a2 = a1 + qst2;
      float x3 = x1 - a2;
      float d3 = q2f[j] - x3;
      float qst3 = x3 + d3;
      float a3 = a2 + qst3;
      qout[j] = a3;
      lsum += (double)d1 * d1 + (double)d2 * d2 + (double)d3 * d3;
    }
  }
  float4 qv = {qout[0], qout[1], qout[2], qout[3]};
  *(float4*)(quant + base) = qv;

#pragma unroll
  for (int off = 1; off < 64; off <<= 1) lsum += __shfl_xor(lsum, off, 64);
  if (lane == 0) {
    wsum[w] = lsum;
    enc0[(size_t)r * KCODES + i0] = 1.0f;
    atomicAdd(&hist[i0], 1u);
  } else if (lane == 1) {
    enc1[(size_t)r * KCODES + i1] = 1.0f;
    atomicAdd(&hist[KCODES + i1], 1u);
  } else if (lane == 2) {
    enc2[(size_t)r * KCODES + i2] = 1.0f;
    atomicAdd(&hist[2 * KCODES + i2], 1u);
  }
  __syncthreads();
  if (threadIdx.x == 0) {
    double bsum = (wsum[0] + wsum[1]) + (wsum[2] + wsum[3]);
    atomicAdd(&loss_slots[blockIdx.x & (NLOSS - 1)], bsum);
  }
}

// ---------------- scalars (separate 1-block kernel — r21-proven) ----------------
__global__ void finalize_k(const unsigned int* __restrict__ hist,
                           const double* __restrict__ loss_slots,
                           float* __restrict__ out_scalars) {
  int lane = threadIdx.x;
  double te = 0.0;
  for (int s = 0; s < NSTAGE; ++s) {
    double e = 0.0;
    for (int j = 0; j < KCODES / 64; ++j) {
      int k = j * 64 + lane;
      float pf = (float)hist[s * KCODES + k] * (1.0f / 65536.0f);
      float sf = __fadd_rn(pf, 1e-10f);
      e += (double)pf * log((double)sf);
    }
#pragma unroll
    for (int off = 1; off < 64; off <<= 1) e += __shfl_xor(e, off, 64);
    te += -e;
  }
  double ls = loss_slots[lane] + loss_slots[64 + lane] +
              loss_slots[128 + lane] + loss_slots[192 + lane];
#pragma unroll
  for (int off = 1; off < 64; off <<= 1) ls += __shfl_xor(ls, off, 64);
  if (lane == 0) {
    double tl = 1.25 * ls * (1.0 / 16777216.0);
    out_scalars[0] = (float)tl;
    out_scalars[1] = (float)te;
  }
}

extern "C" void kernel_launch(void* const* d_in, const int* in_sizes, int n_in,
                              void* d_out, int out_size, void* d_ws, size_t ws_size,
                              hipStream_t stream) {
  const float* data = (const float*)d_in[0];
  const float* cb0 = (const float*)d_in[1];
  const float* cb1 = (const float*)d_in[2];
  const float* cb2 = (const float*)d_in[3];
  const float* cbs[3] = {cb0, cb1, cb2};
  float* out = (float*)d_out;
  float* quant = out;
  float* enc0 = out + (size_t)NROWS * DDIM;
  float* enc1 = enc0 + (size_t)NROWS * KCODES;
  float* enc2 = enc1 + (size_t)NROWS * KCODES;
  float* out_scalars = enc2 + (size_t)NROWS * KCODES;

  // ws: [0) loss_slots f64x256 | 2048) hist u32x1536 | 8192) flagcnt u32x3 |
  //     8320) flagrows i32[3][65536] | 794752) cc f32x1536 |
  //     800896) idx i32[3][N] | 1587328) Ch frag-bf16 3x256KB
  double* loss_slots = (double*)d_ws;
  unsigned int* hist = (unsigned int*)((char*)d_ws + 2048);
  unsigned int* flagcnt = (unsigned int*)((char*)d_ws + 8192);
  int* flagrows = (int*)((char*)d_ws + 8320);
  float* cc = (float*)((char*)d_ws + 794752);
  int* idx0 = (int*)((char*)d_ws + 800896);
  int* idx1 = idx0 + NROWS;
  int* idx2 = idx1 + NROWS;
  int* idxs[3] = {idx0, idx1, idx2};
  unsigned short* Ch = (unsigned short*)((char*)d_ws + 1587328);

  hipMemsetAsync(d_ws, 0, 8320, stream);

  prep_k<<<(NSTAGE * KCODES * 32 + 255) / 256, 256, 0, stream>>>(
      cb0, cb1, cb2, cc, Ch);

  for (int s = 0; s < NSTAGE; ++s) {
    gemm_k<<<NROWS / MB, NTH, 0, stream>>>(
        data,
        (const unsigned short*)((char*)Ch + (size_t)s * 262144),
        cb0, cb1, idx0, idx1, cc + s * KCODES, s,
        idxs[s], flagcnt + s, flagrows + s * MAXFLAG);
    refine_k<<<512, 256, 0, stream>>>(
        data, cbs[s], cb0, cb1, idx0, idx1, cc + s * KCODES, s,
        flagcnt + s, flagrows + s * MAXFLAG, idxs[s]);
  }

  // zero enc region, then scatter the 1s
  hipMemsetAsync(enc0, 0, (size_t)3 * NROWS * KCODES * sizeof(float), stream);

  final_k<<<NROWS / 4, 256, 0, stream>>>(
      data, cb0, cb1, cb2, idx0, idx1, idx2, quant, enc0, enc1, enc2,
      loss_slots, hist);

  finalize_k<<<1, 64, 0, stream>>>(hist, loss_slots, out_scalars);
}